// Round 4
// baseline (1253.551 us; speedup 1.0000x reference)
//
#include <hip/hip_runtime.h>
#include <hip/hip_bf16.h>

#define N_A_NODES 100000
#define N_B_NODES 100000
#define D_FEAT    64
#define HIDDEN    128
#define NE        800000
#define CAP_MAX   48

using bf16 = __hip_bfloat16;
typedef __bf16 bf16x8 __attribute__((ext_vector_type(8)));
typedef float  floatx4 __attribute__((ext_vector_type(4)));

// ---------------------------------------------------------------------------
// dtype-agnostic load/store helpers (external tensors may be fp32 or bf16)
// ---------------------------------------------------------------------------
__device__ __forceinline__ __bf16 f2b(float x) {
    union { bf16 h; __bf16 b; } u;
    u.h = __float2bfloat16(x);
    return u.b;
}
__device__ __forceinline__ bf16x8 load8(const void* p, size_t off, bool f32) {
    if (f32) {
        const float* fp = (const float*)p + off;
        float4 a = *(const float4*)fp;
        float4 b = *(const float4*)(fp + 4);
        bf16x8 r;
        r[0] = f2b(a.x); r[1] = f2b(a.y); r[2] = f2b(a.z); r[3] = f2b(a.w);
        r[4] = f2b(b.x); r[5] = f2b(b.y); r[6] = f2b(b.z); r[7] = f2b(b.w);
        return r;
    }
    return *(const bf16x8*)((const bf16*)p + off);
}
__device__ __forceinline__ float loadf(const void* p, size_t off, bool f32) {
    return f32 ? ((const float*)p)[off]
               : __bfloat162float(((const bf16*)p)[off]);
}
__device__ __forceinline__ void storef(void* p, size_t off, bool f32, float v) {
    if (f32) ((float*)p)[off] = v;
    else     ((bf16*)p)[off] = __float2bfloat16(v);
}

// ---------------------------------------------------------------------------
// Runtime dtype detection (1 thread; wave-uniform flags consumed by all kernels)
// bit0: float tensors are fp32 (else bf16)
// bit1: node_id_A is int64 (else int32)
// bit2: edge arrays are int64 (else int32)
// ---------------------------------------------------------------------------
__global__ void detect(const unsigned int* __restrict__ xA_bits,
                       const unsigned int* __restrict__ idA_bits,
                       const unsigned int* __restrict__ eAB_bits,
                       int* __restrict__ flags)
{
    if (threadIdx.x != 0 || blockIdx.x != 0) return;
    // fp32 vs bf16: low halfword's bf16-exponent field. For bf16 data (N(0,1))
    // it's concentrated in [100,135]; for fp32 mantissa bits it's ~uniform.
    int inr = 0;
    for (int i = 0; i < 256; i++) {
        unsigned e = (xA_bits[i] >> 7) & 0xFF;
        if (e >= 100 && e <= 135) inr++;
    }
    int f32 = (inr < 128) ? 1 : 0;
    // int64 vs int32: values < 2^31, so int64 => every odd word is 0.
    int id64 = 1, e64 = 1;
    for (int i = 0; i < 64; i++) {
        if (idA_bits[2 * i + 1] != 0) id64 = 0;
        if (eAB_bits[2 * i + 1] != 0) e64 = 0;
    }
    flags[0] = f32 | (id64 << 1) | (e64 << 2);
}

// ---------------------------------------------------------------------------
// Build padded adjacency lists (src indices grouped by dst) for both edge dirs.
// cnt* must be zeroed before this kernel.  cap chosen at runtime to fit ws.
// ---------------------------------------------------------------------------
__global__ void build_adj(const int* __restrict__ eAB, const int* __restrict__ eBA,
                          int* __restrict__ adjAB, int* __restrict__ cntB,
                          int* __restrict__ adjBA, int* __restrict__ cntA,
                          int cap, const int* __restrict__ flags)
{
    int st = (flags[0] & 4) ? 2 : 1;   // int64 edges: read low word (LE)
    int e = blockIdx.x * blockDim.x + threadIdx.x;
    if (e < NE) {
        int src = eAB[(size_t)e * st];
        int dst = eAB[(size_t)(NE + e) * st];
        int pos = atomicAdd(&cntB[dst], 1);
        if (pos < cap) adjAB[(size_t)dst * cap + pos] = src;
    } else {
        int e2 = e - NE;
        if (e2 < NE) {
            int src = eBA[(size_t)e2 * st];
            int dst = eBA[(size_t)(NE + e2) * st];
            int pos = atomicAdd(&cntA[dst], 1);
            if (pos < cap) adjBA[(size_t)dst * cap + pos] = src;
        }
    }
}

// ---------------------------------------------------------------------------
// xA = x_A @ linA_W^T + linA_b + emb_A[idA]   (MFMA, K=64, no relu)
// one wave -> 16 rows x 128 cols.  out is internal bf16.
// ---------------------------------------------------------------------------
__global__ __launch_bounds__(256) void fuse_input(
    const void* __restrict__ xin, const int* __restrict__ idA,
    const void* __restrict__ embA, const void* __restrict__ W,
    const void* __restrict__ bias, bf16* __restrict__ out,
    const int* __restrict__ flags)
{
    int fl = flags[0];
    bool f32 = fl & 1;
    int idst = (fl & 2) ? 2 : 1;
    int lane = threadIdx.x & 63;
    int wid  = threadIdx.x >> 6;
    int m0   = (blockIdx.x * 4 + wid) * 16;
    if (m0 >= N_A_NODES) return;
    int r = lane & 15, q = lane >> 4;

    floatx4 acc[8] = {};
#pragma unroll
    for (int s = 0; s < 2; s++) {
        bf16x8 a = load8(xin, (size_t)(m0 + r) * D_FEAT + s * 32 + q * 8, f32);
#pragma unroll
        for (int t = 0; t < 8; t++) {
            bf16x8 b = load8(W, (size_t)(t * 16 + r) * D_FEAT + s * 32 + q * 8, f32);
            acc[t] = __builtin_amdgcn_mfma_f32_16x16x32_bf16(a, b, acc[t], 0, 0, 0);
        }
    }
#pragma unroll
    for (int t = 0; t < 8; t++) {
        int col = t * 16 + r;
        float bf = loadf(bias, col, f32);
#pragma unroll
        for (int rr = 0; rr < 4; rr++) {
            int row = m0 + q * 4 + rr;
            int id = idA[(size_t)row * idst];
            float v = acc[t][rr] + bf + loadf(embA, (size_t)id * HIDDEN + col, f32);
            out[(size_t)row * HIDDEN + col] = __float2bfloat16(v);
        }
    }
}

// ---------------------------------------------------------------------------
// xB = emb_B[idB]  (row gather, 4 elements per thread; out internal bf16)
// ---------------------------------------------------------------------------
__global__ void copy_embB(const void* __restrict__ emb, const int* __restrict__ idB,
                          bf16* __restrict__ out, const int* __restrict__ flags)
{
    bool f32 = flags[0] & 1;
    int t = blockIdx.x * blockDim.x + threadIdx.x;
    int row = t >> 5;          // 32 groups of 4 elements per row
    int g   = t & 31;
    if (row >= N_B_NODES) return;
    size_t s = (size_t)idB[row] * HIDDEN + g * 4;
    size_t d = (size_t)row * HIDDEN + g * 4;
    if (f32) {
        float4 v = *(const float4*)((const float*)emb + s);
        union { bf16 h[4]; uint2 u; } pk;
        pk.h[0] = __float2bfloat16(v.x); pk.h[1] = __float2bfloat16(v.y);
        pk.h[2] = __float2bfloat16(v.z); pk.h[3] = __float2bfloat16(v.w);
        *(uint2*)(out + d) = pk.u;
    } else {
        *(uint2*)(out + d) = *(const uint2*)((const bf16*)emb + s);
    }
}

// ---------------------------------------------------------------------------
// segment mean: one wave per dst node, 2 features per lane, fp32 accumulate.
// feat is internal bf16; out (mAB/mBA, scratch inside d_out) uses external dtype.
// ---------------------------------------------------------------------------
__global__ __launch_bounds__(256) void aggregate(
    const bf16* __restrict__ feat, const int* __restrict__ adj,
    const int* __restrict__ cnt, void* __restrict__ outbase, size_t out_eoff,
    int Ndst, int cap, const int* __restrict__ flags)
{
    bool f32 = flags[0] & 1;
    int wid  = (blockIdx.x * blockDim.x + threadIdx.x) >> 6;
    int lane = threadIdx.x & 63;
    if (wid >= Ndst) return;

    int c = cnt[wid];
    int n = c < cap ? c : cap;
    const int* row = adj + (size_t)wid * cap;

    float a0 = 0.f, a1 = 0.f;
    for (int e = 0; e < n; e++) {
        int s = row[e];
        const __hip_bfloat162* p = (const __hip_bfloat162*)(feat + (size_t)s * HIDDEN);
        float2 f = __bfloat1622float2(p[lane]);
        a0 += f.x;
        a1 += f.y;
    }
    float scale = 1.0f / (float)(c > 1 ? c : 1);
    a0 *= scale;
    a1 *= scale;
    size_t e0 = out_eoff + (size_t)wid * HIDDEN + 2 * lane;
    if (f32) {
        float2* o = (float2*)((float*)outbase + e0);
        *o = make_float2(a0, a1);
    } else {
        __hip_bfloat162 h;
        h.x = __float2bfloat16(a0);
        h.y = __float2bfloat16(a1);
        *(__hip_bfloat162*)((bf16*)outbase + e0) = h;
    }
}

// ---------------------------------------------------------------------------
// out = relu(A1 @ W1^T + bias + A2 @ W2^T)   (fused K=256 MFMA GEMM)
// A1 external dtype (base+element offset), A2 internal bf16, W/bias external
// (indexed by layer), out internal bf16 (out_ext=0) or external (out_ext=1).
// In-place safe for out aliasing A1 or A2: each wave reads only rows it writes.
// ---------------------------------------------------------------------------
__global__ __launch_bounds__(256) void gemm_dual(
    const void* __restrict__ A1base, size_t a1_eoff, const bf16* __restrict__ A2,
    const void* __restrict__ Wl, const void* __restrict__ Wr,
    const void* __restrict__ bl, int layer,
    void* __restrict__ outbase, size_t out_eoff, int out_ext,
    int N, const int* __restrict__ flags)
{
    bool f32  = flags[0] & 1;
    bool outf = out_ext && f32;
    int lane = threadIdx.x & 63;
    int wid  = threadIdx.x >> 6;
    int m0   = (blockIdx.x * 4 + wid) * 16;
    if (m0 >= N) return;
    int r = lane & 15, q = lane >> 4;

    const size_t woff = (size_t)layer * HIDDEN * HIDDEN;
    const size_t boff = (size_t)layer * HIDDEN;

    floatx4 acc[8] = {};
#pragma unroll
    for (int s = 0; s < 4; s++) {
        bf16x8 a = load8(A1base, a1_eoff + (size_t)(m0 + r) * HIDDEN + s * 32 + q * 8, f32);
#pragma unroll
        for (int t = 0; t < 8; t++) {
            bf16x8 b = load8(Wl, woff + (size_t)(t * 16 + r) * HIDDEN + s * 32 + q * 8, f32);
            acc[t] = __builtin_amdgcn_mfma_f32_16x16x32_bf16(a, b, acc[t], 0, 0, 0);
        }
    }
#pragma unroll
    for (int s = 0; s < 4; s++) {
        bf16x8 a = *(const bf16x8*)(A2 + (size_t)(m0 + r) * HIDDEN + s * 32 + q * 8);
#pragma unroll
        for (int t = 0; t < 8; t++) {
            bf16x8 b = load8(Wr, woff + (size_t)(t * 16 + r) * HIDDEN + s * 32 + q * 8, f32);
            acc[t] = __builtin_amdgcn_mfma_f32_16x16x32_bf16(a, b, acc[t], 0, 0, 0);
        }
    }
#pragma unroll
    for (int t = 0; t < 8; t++) {
        int col = t * 16 + r;
        float bf = loadf(bl, boff + col, f32);
#pragma unroll
        for (int rr = 0; rr < 4; rr++) {
            float v = acc[t][rr] + bf;
            v = v > 0.f ? v : 0.f;
            size_t eo = out_eoff + (size_t)(m0 + q * 4 + rr) * HIDDEN + col;
            if (outf) ((float*)outbase)[eo] = v;
            else      ((bf16*)outbase)[eo] = __float2bfloat16(v);
        }
    }
}

// ---------------------------------------------------------------------------
extern "C" void kernel_launch(void* const* d_in, const int* in_sizes, int n_in,
                              void* d_out, int out_size, void* d_ws, size_t ws_size,
                              hipStream_t stream)
{
    const void* x_A  = d_in[0];
    const int*  idA  = (const int*)d_in[1];
    const int*  idB  = (const int*)d_in[2];
    const int*  eAB  = (const int*)d_in[3];
    const int*  eBA  = (const int*)d_in[4];
    const void* embA = d_in[5];
    const void* embB = d_in[6];
    const void* linW = d_in[7];
    const void* linb = d_in[8];
    const void* WlAB = d_in[9];
    const void* blAB = d_in[10];
    const void* WrAB = d_in[11];
    const void* WlBA = d_in[12];
    const void* blBA = d_in[13];
    const void* WrBA = d_in[14];

    // ---- workspace layout ----
    // cnt (0.8 MB) + flags (64 B) + xA (25.6 MB) + xB (25.6 MB) = ~52 MB fixed;
    // adjacency gets the rest: 2 * 100000 * cap * 4 B, cap in [1, 48].
    char* ws = (char*)d_ws;
    int*  cntB  = (int*)(ws + 0);
    int*  cntA  = (int*)(ws + 400000);
    int*  flags = (int*)(ws + 800000);
    bf16* xA    = (bf16*)(ws + 800064);
    bf16* xB    = (bf16*)(ws + 26400064);
    const size_t FIXED = 52000064;
    long long avail = (long long)ws_size - (long long)FIXED;
    int cap = (int)(avail / 800000);
    if (cap > CAP_MAX) cap = CAP_MAX;
    if (cap < 1) cap = 1;
    int* adjAB = (int*)(ws + FIXED);
    int* adjBA = (int*)(ws + FIXED + (size_t)cap * 400000);

    // mAB / mBA live in d_out (element offsets; dtype resolved on device).
    // outA = elements [0, 12.8M), outB = [12.8M, 25.6M).
    const size_t OUTB_EOFF = (size_t)N_A_NODES * HIDDEN;

    (void)hipMemsetAsync(cntB, 0, 800000, stream);  // zeros cntB + cntA

    detect<<<1, 64, 0, stream>>>((const unsigned int*)x_A, (const unsigned int*)idA,
                                 (const unsigned int*)eAB, flags);
    build_adj<<<(2 * NE + 255) / 256, 256, 0, stream>>>(eAB, eBA, adjAB, cntB,
                                                        adjBA, cntA, cap, flags);
    fuse_input<<<(N_A_NODES + 63) / 64, 256, 0, stream>>>(x_A, idA, embA, linW,
                                                          linb, xA, flags);
    copy_embB<<<(N_B_NODES * 32 + 255) / 256, 256, 0, stream>>>(embB, idB, xB, flags);

    for (int l = 0; l < 2; l++) {
        // segment means into d_out scratch: mAB -> outB region, mBA -> outA region
        aggregate<<<(N_B_NODES + 3) / 4, 256, 0, stream>>>(xA, adjAB, cntB, d_out,
                                                           OUTB_EOFF, N_B_NODES, cap, flags);
        aggregate<<<(N_A_NODES + 3) / 4, 256, 0, stream>>>(xB, adjBA, cntA, d_out,
                                                           0, N_A_NODES, cap, flags);

        if (l == 0) {
            // newB -> xB (internal bf16), newA -> xA (internal bf16)
            gemm_dual<<<(N_B_NODES + 63) / 64, 256, 0, stream>>>(
                d_out, OUTB_EOFF, xB, WlAB, WrAB, blAB, 0, xB, 0, 0, N_B_NODES, flags);
            gemm_dual<<<(N_A_NODES + 63) / 64, 256, 0, stream>>>(
                d_out, 0, xA, WlBA, WrBA, blBA, 0, xA, 0, 0, N_A_NODES, flags);
        } else {
            // final: newB -> d_out[outB], newA -> d_out[outA] (external dtype)
            gemm_dual<<<(N_B_NODES + 63) / 64, 256, 0, stream>>>(
                d_out, OUTB_EOFF, xB, WlAB, WrAB, blAB, 1, d_out, OUTB_EOFF, 1, N_B_NODES, flags);
            gemm_dual<<<(N_A_NODES + 63) / 64, 256, 0, stream>>>(
                d_out, 0, xA, WlBA, WrBA, blBA, 1, d_out, 0, 1, N_A_NODES, flags);
        }
    }
}

// Round 5
// 988.134 us; speedup vs baseline: 1.2686x; 1.2686x over previous
//
#include <hip/hip_runtime.h>
#include <hip/hip_bf16.h>

#define N_A_NODES 100000
#define N_B_NODES 100000
#define D_FEAT    64
#define HIDDEN    128
#define NE        800000
#define CAP_MAX   48

using bf16 = __hip_bfloat16;
typedef __bf16 bf16x8 __attribute__((ext_vector_type(8)));
typedef float  floatx4 __attribute__((ext_vector_type(4)));

// ---------------------------------------------------------------------------
// dtype-agnostic helpers (external tensors may be fp32 or bf16)
// ---------------------------------------------------------------------------
__device__ __forceinline__ __bf16 f2b(float x) {
    union { bf16 h; __bf16 b; } u;
    u.h = __float2bfloat16(x);
    return u.b;
}
__device__ __forceinline__ bf16x8 load8(const void* p, size_t off, bool f32) {
    if (f32) {
        const float* fp = (const float*)p + off;
        float4 a = *(const float4*)fp;
        float4 b = *(const float4*)(fp + 4);
        bf16x8 r;
        r[0] = f2b(a.x); r[1] = f2b(a.y); r[2] = f2b(a.z); r[3] = f2b(a.w);
        r[4] = f2b(b.x); r[5] = f2b(b.y); r[6] = f2b(b.z); r[7] = f2b(b.w);
        return r;
    }
    return *(const bf16x8*)((const bf16*)p + off);
}
__device__ __forceinline__ float loadf(const void* p, size_t off, bool f32) {
    return f32 ? ((const float*)p)[off]
               : __bfloat162float(((const bf16*)p)[off]);
}

// ---------------------------------------------------------------------------
// Runtime dtype detection, one wave (parallel; R4's 1-thread version was
// ~80 us of serial load latency).
// bit0: float tensors are fp32 ; bit1: node_id_A int64 ; bit2: edges int64
// ---------------------------------------------------------------------------
__global__ void detect(const unsigned int* __restrict__ xA_bits,
                       const unsigned int* __restrict__ idA_bits,
                       const unsigned int* __restrict__ eAB_bits,
                       int* __restrict__ flags)
{
    int lane = threadIdx.x;
    // fp32 vs bf16: bf16-exponent field of low halfword; N(0,1) bf16 data is
    // concentrated in [100,135], fp32 mantissa bits are ~uniform.
    int inr = 0;
#pragma unroll
    for (int j = 0; j < 4; j++) {
        unsigned e = (xA_bits[lane * 4 + j] >> 7) & 0xFF;
        inr += (e >= 100 && e <= 135) ? 1 : 0;
    }
#pragma unroll
    for (int s = 32; s > 0; s >>= 1) inr += __shfl_down(inr, s);
    // int64 vs int32: values < 2^31 -> int64 => every odd word is 0.
    unsigned long long idnz = __ballot(idA_bits[2 * lane + 1] != 0);
    unsigned long long enz  = __ballot(eAB_bits[2 * lane + 1] != 0);
    if (lane == 0) {
        int f32  = (inr < 128) ? 1 : 0;
        int id64 = (idnz == 0) ? 1 : 0;
        int e64  = (enz == 0) ? 1 : 0;
        flags[0] = f32 | (id64 << 1) | (e64 << 2);
    }
}

// ---------------------------------------------------------------------------
// Convert all weight/bias params to bf16 once (order/sizes fixed, total 139904
// elements into a contiguous bf16 block in ws).
// ---------------------------------------------------------------------------
#define P_LINW  0
#define P_LINB  8192
#define P_WLAB  8320
#define P_BLAB  41088
#define P_WRAB  41344
#define P_WLBA  74112
#define P_BLBA  106880
#define P_WRBA  107136
#define P_TOTAL 139904

__global__ void convert_params(const void* __restrict__ linW, const void* __restrict__ linb,
                               const void* __restrict__ WlAB, const void* __restrict__ blAB,
                               const void* __restrict__ WrAB, const void* __restrict__ WlBA,
                               const void* __restrict__ blBA, const void* __restrict__ WrBA,
                               bf16* __restrict__ dst, const int* __restrict__ flags)
{
    bool f32 = flags[0] & 1;
    int t = blockIdx.x * blockDim.x + threadIdx.x;
    if (t >= P_TOTAL) return;
    const void* src; size_t off;
    if      (t < P_LINB) { src = linW; off = t - P_LINW; }
    else if (t < P_WLAB) { src = linb; off = t - P_LINB; }
    else if (t < P_BLAB) { src = WlAB; off = t - P_WLAB; }
    else if (t < P_WRAB) { src = blAB; off = t - P_BLAB; }
    else if (t < P_WLBA) { src = WrAB; off = t - P_WRAB; }
    else if (t < P_BLBA) { src = WlBA; off = t - P_WLBA; }
    else if (t < P_WRBA) { src = blBA; off = t - P_BLBA; }
    else                 { src = WrBA; off = t - P_WRBA; }
    dst[t] = __float2bfloat16(loadf(src, off, f32));
}

// ---------------------------------------------------------------------------
// Build padded adjacency lists (src grouped by dst), runtime cap.
// ---------------------------------------------------------------------------
__global__ void build_adj(const int* __restrict__ eAB, const int* __restrict__ eBA,
                          int* __restrict__ adjAB, int* __restrict__ cntB,
                          int* __restrict__ adjBA, int* __restrict__ cntA,
                          int cap, const int* __restrict__ flags)
{
    int st = (flags[0] & 4) ? 2 : 1;   // int64 edges: read low word (LE)
    int e = blockIdx.x * blockDim.x + threadIdx.x;
    if (e < NE) {
        int src = eAB[(size_t)e * st];
        int dst = eAB[(size_t)(NE + e) * st];
        int pos = atomicAdd(&cntB[dst], 1);
        if (pos < cap) adjAB[(size_t)dst * cap + pos] = src;
    } else {
        int e2 = e - NE;
        if (e2 < NE) {
            int src = eBA[(size_t)e2 * st];
            int dst = eBA[(size_t)(NE + e2) * st];
            int pos = atomicAdd(&cntA[dst], 1);
            if (pos < cap) adjBA[(size_t)dst * cap + pos] = src;
        }
    }
}

// ---------------------------------------------------------------------------
// xA = x_A @ linA_W^T + linA_b + emb_A[idA]   (MFMA K=64; W/b pre-bf16)
// ---------------------------------------------------------------------------
__global__ __launch_bounds__(256) void fuse_input(
    const void* __restrict__ xin, const int* __restrict__ idA,
    const void* __restrict__ embA, const bf16* __restrict__ Wb,
    const bf16* __restrict__ bb, bf16* __restrict__ out,
    const int* __restrict__ flags)
{
    int fl = flags[0];
    bool f32 = fl & 1;
    int idst = (fl & 2) ? 2 : 1;
    int lane = threadIdx.x & 63;
    int wid  = threadIdx.x >> 6;
    int m0   = (blockIdx.x * 4 + wid) * 16;
    if (m0 >= N_A_NODES) return;
    int r = lane & 15, q = lane >> 4;

    floatx4 acc[8] = {};
#pragma unroll
    for (int s = 0; s < 2; s++) {
        bf16x8 a = load8(xin, (size_t)(m0 + r) * D_FEAT + s * 32 + q * 8, f32);
#pragma unroll
        for (int t = 0; t < 8; t++) {
            bf16x8 b = *(const bf16x8*)(Wb + (size_t)(t * 16 + r) * D_FEAT + s * 32 + q * 8);
            acc[t] = __builtin_amdgcn_mfma_f32_16x16x32_bf16(a, b, acc[t], 0, 0, 0);
        }
    }
#pragma unroll
    for (int t = 0; t < 8; t++) {
        int col = t * 16 + r;
        float bf = __bfloat162float(bb[col]);
#pragma unroll
        for (int rr = 0; rr < 4; rr++) {
            int row = m0 + q * 4 + rr;
            int id = idA[(size_t)row * idst];
            float v = acc[t][rr] + bf + loadf(embA, (size_t)id * HIDDEN + col, f32);
            out[(size_t)row * HIDDEN + col] = __float2bfloat16(v);
        }
    }
}

// ---------------------------------------------------------------------------
// xB = emb_B[idB]  (row gather, 4 elements/thread)
// ---------------------------------------------------------------------------
__global__ void copy_embB(const void* __restrict__ emb, const int* __restrict__ idB,
                          bf16* __restrict__ out, const int* __restrict__ flags)
{
    bool f32 = flags[0] & 1;
    int t = blockIdx.x * blockDim.x + threadIdx.x;
    int row = t >> 5;
    int g   = t & 31;
    if (row >= N_B_NODES) return;
    size_t s = (size_t)idB[row] * HIDDEN + g * 4;
    size_t d = (size_t)row * HIDDEN + g * 4;
    if (f32) {
        float4 v = *(const float4*)((const float*)emb + s);
        union { bf16 h[4]; uint2 u; } pk;
        pk.h[0] = __float2bfloat16(v.x); pk.h[1] = __float2bfloat16(v.y);
        pk.h[2] = __float2bfloat16(v.z); pk.h[3] = __float2bfloat16(v.w);
        *(uint2*)(out + d) = pk.u;
    } else {
        *(uint2*)(out + d) = *(const uint2*)((const bf16*)emb + s);
    }
}

// ---------------------------------------------------------------------------
// segment mean: one wave per dst node, fp32 accumulate.
// m_mode 0: store bf16 into ws buffer; m_mode 1: store external dtype @d_out.
// ---------------------------------------------------------------------------
__global__ __launch_bounds__(256) void aggregate(
    const bf16* __restrict__ feat, const int* __restrict__ adj,
    const int* __restrict__ cnt, void* __restrict__ outbase, size_t out_eoff,
    int m_mode, int Ndst, int cap, const int* __restrict__ flags)
{
    bool f32sel = m_mode ? (flags[0] & 1) : false;
    int wid  = (blockIdx.x * blockDim.x + threadIdx.x) >> 6;
    int lane = threadIdx.x & 63;
    if (wid >= Ndst) return;

    int c = cnt[wid];
    int n = c < cap ? c : cap;
    const int* row = adj + (size_t)wid * cap;

    float a0 = 0.f, a1 = 0.f;
    for (int e = 0; e < n; e++) {
        int s = row[e];
        const __hip_bfloat162* p = (const __hip_bfloat162*)(feat + (size_t)s * HIDDEN);
        float2 f = __bfloat1622float2(p[lane]);
        a0 += f.x;
        a1 += f.y;
    }
    float scale = 1.0f / (float)(c > 1 ? c : 1);
    a0 *= scale;
    a1 *= scale;
    size_t e0 = out_eoff + (size_t)wid * HIDDEN + 2 * lane;
    if (f32sel) {
        *(float2*)((float*)outbase + e0) = make_float2(a0, a1);
    } else {
        __hip_bfloat162 h;
        h.x = __float2bfloat16(a0);
        h.y = __float2bfloat16(a1);
        *(__hip_bfloat162*)((bf16*)outbase + e0) = h;
    }
}

// ---------------------------------------------------------------------------
// out = relu(A1 @ W1^T + bias + A2 @ W2^T)   (fused K=256 MFMA GEMM)
// A1: bf16 (a1_mode 0) or external dtype (a1_mode 1).  A2/W/b: bf16.
// out: internal bf16 (out_ext 0) or external dtype (out_ext 1).
// In-place safe (out aliasing A1/A2): each wave reads only rows it writes.
// ---------------------------------------------------------------------------
__global__ __launch_bounds__(256) void gemm_dual(
    const void* __restrict__ A1base, size_t a1_eoff, int a1_mode,
    const bf16* __restrict__ A2,
    const bf16* __restrict__ W1, const bf16* __restrict__ W2,
    const bf16* __restrict__ bias,
    void* __restrict__ outbase, size_t out_eoff, int out_ext,
    int N, const int* __restrict__ flags)
{
    bool extf32 = flags[0] & 1;
    bool a1f32  = a1_mode && extf32;
    bool outf   = out_ext && extf32;
    int lane = threadIdx.x & 63;
    int wid  = threadIdx.x >> 6;
    int m0   = (blockIdx.x * 4 + wid) * 16;
    if (m0 >= N) return;
    int r = lane & 15, q = lane >> 4;

    floatx4 acc[8] = {};
#pragma unroll
    for (int s = 0; s < 4; s++) {
        bf16x8 a = load8(A1base, a1_eoff + (size_t)(m0 + r) * HIDDEN + s * 32 + q * 8, a1f32);
#pragma unroll
        for (int t = 0; t < 8; t++) {
            bf16x8 b = *(const bf16x8*)(W1 + (size_t)(t * 16 + r) * HIDDEN + s * 32 + q * 8);
            acc[t] = __builtin_amdgcn_mfma_f32_16x16x32_bf16(a, b, acc[t], 0, 0, 0);
        }
    }
#pragma unroll
    for (int s = 0; s < 4; s++) {
        bf16x8 a = *(const bf16x8*)(A2 + (size_t)(m0 + r) * HIDDEN + s * 32 + q * 8);
#pragma unroll
        for (int t = 0; t < 8; t++) {
            bf16x8 b = *(const bf16x8*)(W2 + (size_t)(t * 16 + r) * HIDDEN + s * 32 + q * 8);
            acc[t] = __builtin_amdgcn_mfma_f32_16x16x32_bf16(a, b, acc[t], 0, 0, 0);
        }
    }
#pragma unroll
    for (int t = 0; t < 8; t++) {
        int col = t * 16 + r;
        float bf = __bfloat162float(bias[col]);
#pragma unroll
        for (int rr = 0; rr < 4; rr++) {
            float v = acc[t][rr] + bf;
            v = v > 0.f ? v : 0.f;
            size_t eo = out_eoff + (size_t)(m0 + q * 4 + rr) * HIDDEN + col;
            if (outf) ((float*)outbase)[eo] = v;
            else      ((bf16*)outbase)[eo] = __float2bfloat16(v);
        }
    }
}

// ---------------------------------------------------------------------------
extern "C" void kernel_launch(void* const* d_in, const int* in_sizes, int n_in,
                              void* d_out, int out_size, void* d_ws, size_t ws_size,
                              hipStream_t stream)
{
    const void* x_A  = d_in[0];
    const int*  idA  = (const int*)d_in[1];
    const int*  idB  = (const int*)d_in[2];
    const int*  eAB  = (const int*)d_in[3];
    const int*  eBA  = (const int*)d_in[4];
    const void* embA = d_in[5];
    const void* embB = d_in[6];

    // ---- workspace layout ----
    char* ws = (char*)d_ws;
    int*  cntB  = (int*)(ws + 0);           // 400000 B
    int*  cntA  = (int*)(ws + 400000);      // 400000 B
    int*  flags = (int*)(ws + 800000);      // 64 B
    bf16* pblk  = (bf16*)(ws + 800064);     // 279808 B of bf16 params
    const size_t XA_OFF = 1080000;
    const size_t XB_OFF = XA_OFF + 25600000;   // 26680000
    const size_t M_OFF  = XB_OFF + 25600000;   // 52280000
    bf16* xA = (bf16*)(ws + XA_OFF);
    bf16* xB = (bf16*)(ws + XB_OFF);

    // mAB/mBA: prefer bf16 in ws; fall back to external-dtype scratch in d_out
    // (the R4-proven path) if ws is too small to also hold a decent adjacency.
    const size_t ADJ_M = M_OFF + 51200000;     // 103480000
    long long cap_m = ((long long)ws_size - (long long)ADJ_M) / 800000;
    int m_in_ws = (cap_m >= 16) ? 1 : 0;
    size_t adj_off = m_in_ws ? ADJ_M : M_OFF;
    long long capl = ((long long)ws_size - (long long)adj_off) / 800000;
    int cap = (int)capl;
    if (cap > CAP_MAX) cap = CAP_MAX;
    if (cap < 1) cap = 1;
    int* adjAB = (int*)(ws + adj_off);
    int* adjBA = (int*)(ws + adj_off + (size_t)cap * 400000);

    const size_t OUTB_EOFF = (size_t)N_A_NODES * HIDDEN;
    void*  mAB_base = m_in_ws ? (void*)(ws + M_OFF)            : d_out;
    void*  mBA_base = m_in_ws ? (void*)(ws + M_OFF + 25600000) : d_out;
    size_t mAB_eoff = m_in_ws ? 0 : OUTB_EOFF;
    size_t mBA_eoff = 0;
    int    m_mode   = m_in_ws ? 0 : 1;

    // bf16 param slices
    bf16* linWb = pblk + P_LINW;
    bf16* linbb = pblk + P_LINB;
    bf16* WlABb = pblk + P_WLAB;
    bf16* blABb = pblk + P_BLAB;
    bf16* WrABb = pblk + P_WRAB;
    bf16* WlBAb = pblk + P_WLBA;
    bf16* blBAb = pblk + P_BLBA;
    bf16* WrBAb = pblk + P_WRBA;

    (void)hipMemsetAsync(cntB, 0, 800000, stream);  // zeros cntB + cntA

    detect<<<1, 64, 0, stream>>>((const unsigned int*)x_A, (const unsigned int*)idA,
                                 (const unsigned int*)eAB, flags);
    convert_params<<<(P_TOTAL + 255) / 256, 256, 0, stream>>>(
        d_in[7], d_in[8], d_in[9], d_in[10], d_in[11], d_in[12], d_in[13], d_in[14],
        pblk, flags);
    build_adj<<<(2 * NE + 255) / 256, 256, 0, stream>>>(eAB, eBA, adjAB, cntB,
                                                        adjBA, cntA, cap, flags);
    fuse_input<<<(N_A_NODES + 63) / 64, 256, 0, stream>>>(x_A, idA, embA, linWb,
                                                          linbb, xA, flags);
    copy_embB<<<(N_B_NODES * 32 + 255) / 256, 256, 0, stream>>>(embB, idB, xB, flags);

    for (int l = 0; l < 2; l++) {
        bf16* wl_ab = WlABb + (size_t)l * HIDDEN * HIDDEN;
        bf16* wr_ab = WrABb + (size_t)l * HIDDEN * HIDDEN;
        bf16* wl_ba = WlBAb + (size_t)l * HIDDEN * HIDDEN;
        bf16* wr_ba = WrBAb + (size_t)l * HIDDEN * HIDDEN;
        bf16* b_ab  = blABb + (size_t)l * HIDDEN;
        bf16* b_ba  = blBAb + (size_t)l * HIDDEN;

        aggregate<<<(N_B_NODES + 3) / 4, 256, 0, stream>>>(
            xA, adjAB, cntB, mAB_base, mAB_eoff, m_mode, N_B_NODES, cap, flags);
        aggregate<<<(N_A_NODES + 3) / 4, 256, 0, stream>>>(
            xB, adjBA, cntA, mBA_base, mBA_eoff, m_mode, N_A_NODES, cap, flags);

        if (l == 0) {
            gemm_dual<<<(N_B_NODES + 63) / 64, 256, 0, stream>>>(
                mAB_base, mAB_eoff, m_mode, xB, wl_ab, wr_ab, b_ab,
                xB, 0, 0, N_B_NODES, flags);
            gemm_dual<<<(N_A_NODES + 63) / 64, 256, 0, stream>>>(
                mBA_base, mBA_eoff, m_mode, xA, wl_ba, wr_ba, b_ba,
                xA, 0, 0, N_A_NODES, flags);
        } else {
            gemm_dual<<<(N_B_NODES + 63) / 64, 256, 0, stream>>>(
                mAB_base, mAB_eoff, m_mode, xB, wl_ab, wr_ab, b_ab,
                d_out, OUTB_EOFF, 1, N_B_NODES, flags);
            gemm_dual<<<(N_A_NODES + 63) / 64, 256, 0, stream>>>(
                mBA_base, mBA_eoff, m_mode, xA, wl_ba, wr_ba, b_ba,
                d_out, 0, 1, N_A_NODES, flags);
        }
    }
}

// Round 6
// 982.211 us; speedup vs baseline: 1.2763x; 1.0060x over previous
//
#include <hip/hip_runtime.h>
#include <hip/hip_bf16.h>

#define N_A_NODES 100000
#define N_B_NODES 100000
#define D_FEAT    64
#define HIDDEN    128
#define NE        800000
#define CAP_MAX   48
#define NSLICE    100000   // column-major adjacency slice stride (= nodes/type)

using bf16 = __hip_bfloat16;
typedef __bf16 bf16x8 __attribute__((ext_vector_type(8)));
typedef float  floatx4 __attribute__((ext_vector_type(4)));

// ---------------------------------------------------------------------------
// dtype-agnostic helpers (external tensors may be fp32 or bf16)
// ---------------------------------------------------------------------------
__device__ __forceinline__ __bf16 f2b(float x) {
    union { bf16 h; __bf16 b; } u;
    u.h = __float2bfloat16(x);
    return u.b;
}
__device__ __forceinline__ bf16x8 load8(const void* p, size_t off, bool f32) {
    if (f32) {
        const float* fp = (const float*)p + off;
        float4 a = *(const float4*)fp;
        float4 b = *(const float4*)(fp + 4);
        bf16x8 r;
        r[0] = f2b(a.x); r[1] = f2b(a.y); r[2] = f2b(a.z); r[3] = f2b(a.w);
        r[4] = f2b(b.x); r[5] = f2b(b.y); r[6] = f2b(b.z); r[7] = f2b(b.w);
        return r;
    }
    return *(const bf16x8*)((const bf16*)p + off);
}
__device__ __forceinline__ float loadf(const void* p, size_t off, bool f32) {
    return f32 ? ((const float*)p)[off]
               : __bfloat162float(((const bf16*)p)[off]);
}

// ---------------------------------------------------------------------------
// Runtime dtype detection, one wave.
// bit0: float tensors are fp32 ; bit1: node_id_A int64 ; bit2: edges int64
// ---------------------------------------------------------------------------
__global__ void detect(const unsigned int* __restrict__ xA_bits,
                       const unsigned int* __restrict__ idA_bits,
                       const unsigned int* __restrict__ eAB_bits,
                       int* __restrict__ flags)
{
    int lane = threadIdx.x;
    int inr = 0;
#pragma unroll
    for (int j = 0; j < 4; j++) {
        unsigned e = (xA_bits[lane * 4 + j] >> 7) & 0xFF;
        inr += (e >= 100 && e <= 135) ? 1 : 0;
    }
#pragma unroll
    for (int s = 32; s > 0; s >>= 1) inr += __shfl_down(inr, s);
    unsigned long long idnz = __ballot(idA_bits[2 * lane + 1] != 0);
    unsigned long long enz  = __ballot(eAB_bits[2 * lane + 1] != 0);
    if (lane == 0) {
        int f32  = (inr < 128) ? 1 : 0;
        int id64 = (idnz == 0) ? 1 : 0;
        int e64  = (enz == 0) ? 1 : 0;
        flags[0] = f32 | (id64 << 1) | (e64 << 2);
    }
}

// ---------------------------------------------------------------------------
// Convert all weight/bias params to bf16 once.
// ---------------------------------------------------------------------------
#define P_LINW  0
#define P_LINB  8192
#define P_WLAB  8320
#define P_BLAB  41088
#define P_WRAB  41344
#define P_WLBA  74112
#define P_BLBA  106880
#define P_WRBA  107136
#define P_TOTAL 139904

__global__ void convert_params(const void* __restrict__ linW, const void* __restrict__ linb,
                               const void* __restrict__ WlAB, const void* __restrict__ blAB,
                               const void* __restrict__ WrAB, const void* __restrict__ WlBA,
                               const void* __restrict__ blBA, const void* __restrict__ WrBA,
                               bf16* __restrict__ dst, const int* __restrict__ flags)
{
    bool f32 = flags[0] & 1;
    int t = blockIdx.x * blockDim.x + threadIdx.x;
    if (t >= P_TOTAL) return;
    const void* src; size_t off;
    if      (t < P_LINB) { src = linW; off = t - P_LINW; }
    else if (t < P_WLAB) { src = linb; off = t - P_LINB; }
    else if (t < P_BLAB) { src = WlAB; off = t - P_WLAB; }
    else if (t < P_WRAB) { src = blAB; off = t - P_BLAB; }
    else if (t < P_WLBA) { src = WrAB; off = t - P_WRAB; }
    else if (t < P_BLBA) { src = WlBA; off = t - P_WLBA; }
    else if (t < P_WRBA) { src = blBA; off = t - P_BLBA; }
    else                 { src = WrBA; off = t - P_WRBA; }
    dst[t] = __float2bfloat16(loadf(src, off, f32));
}

// ---------------------------------------------------------------------------
// Build COLUMN-MAJOR padded adjacency: adj[pos*NSLICE + dst] = src.
// Hot write window = first ~16 slices x 400 KB -> L2 write-combining
// (row-major R5 layout scattered over 38 MB: 95 MB WRITE_SIZE, 140 us).
// ---------------------------------------------------------------------------
__global__ void build_adj(const int* __restrict__ eAB, const int* __restrict__ eBA,
                          int* __restrict__ adjAB, int* __restrict__ cntB,
                          int* __restrict__ adjBA, int* __restrict__ cntA,
                          int cap, const int* __restrict__ flags)
{
    int st = (flags[0] & 4) ? 2 : 1;   // int64 edges: read low word (LE)
    int e = blockIdx.x * blockDim.x + threadIdx.x;
    if (e < NE) {
        int src = eAB[(size_t)e * st];
        int dst = eAB[(size_t)(NE + e) * st];
        int pos = atomicAdd(&cntB[dst], 1);
        if (pos < cap) adjAB[(size_t)pos * NSLICE + dst] = src;
    } else {
        int e2 = e - NE;
        if (e2 < NE) {
            int src = eBA[(size_t)e2 * st];
            int dst = eBA[(size_t)(NE + e2) * st];
            int pos = atomicAdd(&cntA[dst], 1);
            if (pos < cap) adjBA[(size_t)pos * NSLICE + dst] = src;
        }
    }
}

// ---------------------------------------------------------------------------
// xA = x_A @ linA_W^T + linA_b + emb_A[idA]   (MFMA K=64; W/b pre-bf16)
// ---------------------------------------------------------------------------
__global__ __launch_bounds__(256) void fuse_input(
    const void* __restrict__ xin, const int* __restrict__ idA,
    const void* __restrict__ embA, const bf16* __restrict__ Wb,
    const bf16* __restrict__ bb, bf16* __restrict__ out,
    const int* __restrict__ flags)
{
    int fl = flags[0];
    bool f32 = fl & 1;
    int idst = (fl & 2) ? 2 : 1;
    int lane = threadIdx.x & 63;
    int wid  = threadIdx.x >> 6;
    int m0   = (blockIdx.x * 4 + wid) * 16;
    if (m0 >= N_A_NODES) return;
    int r = lane & 15, q = lane >> 4;

    floatx4 acc[8] = {};
#pragma unroll
    for (int s = 0; s < 2; s++) {
        bf16x8 a = load8(xin, (size_t)(m0 + r) * D_FEAT + s * 32 + q * 8, f32);
#pragma unroll
        for (int t = 0; t < 8; t++) {
            bf16x8 b = *(const bf16x8*)(Wb + (size_t)(t * 16 + r) * D_FEAT + s * 32 + q * 8);
            acc[t] = __builtin_amdgcn_mfma_f32_16x16x32_bf16(a, b, acc[t], 0, 0, 0);
        }
    }
#pragma unroll
    for (int t = 0; t < 8; t++) {
        int col = t * 16 + r;
        float bf = __bfloat162float(bb[col]);
#pragma unroll
        for (int rr = 0; rr < 4; rr++) {
            int row = m0 + q * 4 + rr;
            int id = idA[(size_t)row * idst];
            float v = acc[t][rr] + bf + loadf(embA, (size_t)id * HIDDEN + col, f32);
            out[(size_t)row * HIDDEN + col] = __float2bfloat16(v);
        }
    }
}

// ---------------------------------------------------------------------------
// xB = emb_B[idB]  (row gather, 4 elements/thread)
// ---------------------------------------------------------------------------
__global__ void copy_embB(const void* __restrict__ emb, const int* __restrict__ idB,
                          bf16* __restrict__ out, const int* __restrict__ flags)
{
    bool f32 = flags[0] & 1;
    int t = blockIdx.x * blockDim.x + threadIdx.x;
    int row = t >> 5;
    int g   = t & 31;
    if (row >= N_B_NODES) return;
    size_t s = (size_t)idB[row] * HIDDEN + g * 4;
    size_t d = (size_t)row * HIDDEN + g * 4;
    if (f32) {
        float4 v = *(const float4*)((const float*)emb + s);
        union { bf16 h[4]; uint2 u; } pk;
        pk.h[0] = __float2bfloat16(v.x); pk.h[1] = __float2bfloat16(v.y);
        pk.h[2] = __float2bfloat16(v.z); pk.h[3] = __float2bfloat16(v.w);
        *(uint2*)(out + d) = pk.u;
    } else {
        *(uint2*)(out + d) = *(const uint2*)((const bf16*)emb + s);
    }
}

// ---------------------------------------------------------------------------
// segment mean: one wave per dst node, fp32 accumulate; column-major adj.
// m_mode 0: store bf16 into ws buffer; m_mode 1: store external dtype @d_out.
// ---------------------------------------------------------------------------
__global__ __launch_bounds__(256) void aggregate(
    const bf16* __restrict__ feat, const int* __restrict__ adj,
    const int* __restrict__ cnt, void* __restrict__ outbase, size_t out_eoff,
    int m_mode, int Ndst, int cap, const int* __restrict__ flags)
{
    bool f32sel = m_mode ? (flags[0] & 1) : false;
    int wid  = (blockIdx.x * blockDim.x + threadIdx.x) >> 6;
    int lane = threadIdx.x & 63;
    if (wid >= Ndst) return;

    int c = cnt[wid];
    int n = c < cap ? c : cap;

    float a0 = 0.f, a1 = 0.f;
    for (int e = 0; e < n; e++) {
        int s = adj[(size_t)e * NSLICE + wid];
        const __hip_bfloat162* p = (const __hip_bfloat162*)(feat + (size_t)s * HIDDEN);
        float2 f = __bfloat1622float2(p[lane]);
        a0 += f.x;
        a1 += f.y;
    }
    float scale = 1.0f / (float)(c > 1 ? c : 1);
    a0 *= scale;
    a1 *= scale;
    size_t e0 = out_eoff + (size_t)wid * HIDDEN + 2 * lane;
    if (f32sel) {
        *(float2*)((float*)outbase + e0) = make_float2(a0, a1);
    } else {
        __hip_bfloat162 h;
        h.x = __float2bfloat16(a0);
        h.y = __float2bfloat16(a1);
        *(__hip_bfloat162*)((bf16*)outbase + e0) = h;
    }
}

// ---------------------------------------------------------------------------
// out = relu(A1 @ W1^T + bias + A2 @ W2^T)   (fused K=256 MFMA GEMM)
// A1: bf16 (a1_mode 0) or external dtype (a1_mode 1).  A2/W/b: bf16.
// out: internal bf16 (out_ext 0) or external dtype (out_ext 1).
// In-place safe (out aliasing A1/A2): each wave reads only rows it writes.
// ---------------------------------------------------------------------------
__global__ __launch_bounds__(256) void gemm_dual(
    const void* __restrict__ A1base, size_t a1_eoff, int a1_mode,
    const bf16* __restrict__ A2,
    const bf16* __restrict__ W1, const bf16* __restrict__ W2,
    const bf16* __restrict__ bias,
    void* __restrict__ outbase, size_t out_eoff, int out_ext,
    int N, const int* __restrict__ flags)
{
    bool extf32 = flags[0] & 1;
    bool a1f32  = a1_mode && extf32;
    bool outf   = out_ext && extf32;
    int lane = threadIdx.x & 63;
    int wid  = threadIdx.x >> 6;
    int m0   = (blockIdx.x * 4 + wid) * 16;
    if (m0 >= N) return;
    int r = lane & 15, q = lane >> 4;

    floatx4 acc[8] = {};
#pragma unroll
    for (int s = 0; s < 4; s++) {
        bf16x8 a = load8(A1base, a1_eoff + (size_t)(m0 + r) * HIDDEN + s * 32 + q * 8, a1f32);
#pragma unroll
        for (int t = 0; t < 8; t++) {
            bf16x8 b = *(const bf16x8*)(W1 + (size_t)(t * 16 + r) * HIDDEN + s * 32 + q * 8);
            acc[t] = __builtin_amdgcn_mfma_f32_16x16x32_bf16(a, b, acc[t], 0, 0, 0);
        }
    }
#pragma unroll
    for (int s = 0; s < 4; s++) {
        bf16x8 a = *(const bf16x8*)(A2 + (size_t)(m0 + r) * HIDDEN + s * 32 + q * 8);
#pragma unroll
        for (int t = 0; t < 8; t++) {
            bf16x8 b = *(const bf16x8*)(W2 + (size_t)(t * 16 + r) * HIDDEN + s * 32 + q * 8);
            acc[t] = __builtin_amdgcn_mfma_f32_16x16x32_bf16(a, b, acc[t], 0, 0, 0);
        }
    }
#pragma unroll
    for (int t = 0; t < 8; t++) {
        int col = t * 16 + r;
        float bf = __bfloat162float(bias[col]);
#pragma unroll
        for (int rr = 0; rr < 4; rr++) {
            float v = acc[t][rr] + bf;
            v = v > 0.f ? v : 0.f;
            size_t eo = out_eoff + (size_t)(m0 + q * 4 + rr) * HIDDEN + col;
            if (outf) ((float*)outbase)[eo] = v;
            else      ((bf16*)outbase)[eo] = __float2bfloat16(v);
        }
    }
}

// ---------------------------------------------------------------------------
extern "C" void kernel_launch(void* const* d_in, const int* in_sizes, int n_in,
                              void* d_out, int out_size, void* d_ws, size_t ws_size,
                              hipStream_t stream)
{
    const void* x_A  = d_in[0];
    const int*  idA  = (const int*)d_in[1];
    const int*  idB  = (const int*)d_in[2];
    const int*  eAB  = (const int*)d_in[3];
    const int*  eBA  = (const int*)d_in[4];
    const void* embA = d_in[5];
    const void* embB = d_in[6];

    // ---- workspace layout ----
    char* ws = (char*)d_ws;
    int*  cntB  = (int*)(ws + 0);           // 400000 B
    int*  cntA  = (int*)(ws + 400000);      // 400000 B
    int*  flags = (int*)(ws + 800000);      // 64 B
    bf16* pblk  = (bf16*)(ws + 800064);     // 279808 B of bf16 params
    const size_t XA_OFF = 1080000;
    const size_t XB_OFF = XA_OFF + 25600000;   // 26680000
    const size_t M_OFF  = XB_OFF + 25600000;   // 52280000
    bf16* xA = (bf16*)(ws + XA_OFF);
    bf16* xB = (bf16*)(ws + XB_OFF);

    // mAB/mBA: prefer bf16 in ws; fall back to external-dtype scratch in d_out
    // if ws is too small to also hold a decent adjacency.
    const size_t ADJ_M = M_OFF + 51200000;     // 103480000
    long long cap_m = ((long long)ws_size - (long long)ADJ_M) / 800000;
    int m_in_ws = (cap_m >= 16) ? 1 : 0;
    size_t adj_off = m_in_ws ? ADJ_M : M_OFF;
    long long capl = ((long long)ws_size - (long long)adj_off) / 800000;
    int cap = (int)capl;
    if (cap > CAP_MAX) cap = CAP_MAX;
    if (cap < 1) cap = 1;
    int* adjAB = (int*)(ws + adj_off);
    int* adjBA = (int*)(ws + adj_off + (size_t)cap * 400000);

    const size_t OUTB_EOFF = (size_t)N_A_NODES * HIDDEN;
    void*  mAB_base = m_in_ws ? (void*)(ws + M_OFF)            : d_out;
    void*  mBA_base = m_in_ws ? (void*)(ws + M_OFF + 25600000) : d_out;
    size_t mAB_eoff = m_in_ws ? 0 : OUTB_EOFF;
    size_t mBA_eoff = 0;
    int    m_mode   = m_in_ws ? 0 : 1;

    // bf16 param slices
    bf16* linWb = pblk + P_LINW;
    bf16* linbb = pblk + P_LINB;
    bf16* WlABb = pblk + P_WLAB;
    bf16* blABb = pblk + P_BLAB;
    bf16* WrABb = pblk + P_WRAB;
    bf16* WlBAb = pblk + P_WLBA;
    bf16* blBAb = pblk + P_BLBA;
    bf16* WrBAb = pblk + P_WRBA;

    (void)hipMemsetAsync(cntB, 0, 800000, stream);  // zeros cntB + cntA

    detect<<<1, 64, 0, stream>>>((const unsigned int*)x_A, (const unsigned int*)idA,
                                 (const unsigned int*)eAB, flags);
    convert_params<<<(P_TOTAL + 255) / 256, 256, 0, stream>>>(
        d_in[7], d_in[8], d_in[9], d_in[10], d_in[11], d_in[12], d_in[13], d_in[14],
        pblk, flags);
    build_adj<<<(2 * NE + 255) / 256, 256, 0, stream>>>(eAB, eBA, adjAB, cntB,
                                                        adjBA, cntA, cap, flags);
    fuse_input<<<(N_A_NODES + 63) / 64, 256, 0, stream>>>(x_A, idA, embA, linWb,
                                                          linbb, xA, flags);
    copy_embB<<<(N_B_NODES * 32 + 255) / 256, 256, 0, stream>>>(embB, idB, xB, flags);

    for (int l = 0; l < 2; l++) {
        bf16* wl_ab = WlABb + (size_t)l * HIDDEN * HIDDEN;
        bf16* wr_ab = WrABb + (size_t)l * HIDDEN * HIDDEN;
        bf16* wl_ba = WlBAb + (size_t)l * HIDDEN * HIDDEN;
        bf16* wr_ba = WrBAb + (size_t)l * HIDDEN * HIDDEN;
        bf16* b_ab  = blABb + (size_t)l * HIDDEN;
        bf16* b_ba  = blBAb + (size_t)l * HIDDEN;

        aggregate<<<(N_B_NODES + 3) / 4, 256, 0, stream>>>(
            xA, adjAB, cntB, mAB_base, mAB_eoff, m_mode, N_B_NODES, cap, flags);
        aggregate<<<(N_A_NODES + 3) / 4, 256, 0, stream>>>(
            xB, adjBA, cntA, mBA_base, mBA_eoff, m_mode, N_A_NODES, cap, flags);

        if (l == 0) {
            gemm_dual<<<(N_B_NODES + 63) / 64, 256, 0, stream>>>(
                mAB_base, mAB_eoff, m_mode, xB, wl_ab, wr_ab, b_ab,
                xB, 0, 0, N_B_NODES, flags);
            gemm_dual<<<(N_A_NODES + 63) / 64, 256, 0, stream>>>(
                mBA_base, mBA_eoff, m_mode, xA, wl_ba, wr_ba, b_ba,
                xA, 0, 0, N_A_NODES, flags);
        } else {
            gemm_dual<<<(N_B_NODES + 63) / 64, 256, 0, stream>>>(
                mAB_base, mAB_eoff, m_mode, xB, wl_ab, wr_ab, b_ab,
                d_out, OUTB_EOFF, 1, N_B_NODES, flags);
            gemm_dual<<<(N_A_NODES + 63) / 64, 256, 0, stream>>>(
                mBA_base, mBA_eoff, m_mode, xA, wl_ba, wr_ba, b_ba,
                d_out, 0, 1, N_A_NODES, flags);
        }
    }
}